// Round 7
// baseline (280.711 us; speedup 1.0000x reference)
//
#include <hip/hip_runtime.h>
#include <math.h>

#define LQ 2048
#define DM 1024
#define NH 16
#define DH 64
#define LR 4095  // 2*LQ-1

typedef __attribute__((ext_vector_type(4))) float f4v;
typedef __attribute__((ext_vector_type(8))) short s8v;
typedef __attribute__((ext_vector_type(2))) unsigned short us2;
typedef __attribute__((ext_vector_type(8))) unsigned short us8;
typedef __attribute__((ext_vector_type(2))) unsigned int u32x2;
typedef __attribute__((ext_vector_type(4))) unsigned int u32x4;

__device__ __forceinline__ unsigned short f2bf(float x) {
    unsigned int u = __float_as_uint(x);
    return (unsigned short)((u + 0x7FFFu + ((u >> 16) & 1u)) >> 16);
}
__device__ __forceinline__ float bf2f(unsigned short s) {
    return __uint_as_float(((unsigned int)s) << 16);
}
__device__ __forceinline__ unsigned cvtpk(float lo, float hi) {
    unsigned r;
    asm("v_cvt_pk_bf16_f32 %0, %1, %2" : "=v"(r) : "v"(lo), "v"(hi));
    return r;
}
// DPP rotate within 16-lane row (VALU pipe)
template<int CTRL>
__device__ __forceinline__ float rot16(float x) {
    return __uint_as_float((unsigned)__builtin_amdgcn_update_dpp(
        0, (int)__float_as_uint(x), CTRL, 0xF, 0xF, false));
}
#define GLOAD16(g, l) __builtin_amdgcn_global_load_lds((g), (l), 16, 0, 0)
// fence for cross-lane LDS handoff within a wave (load-bearing! see r5 NaN)
#define WAVE_LDS_FENCE() do { \
    asm volatile("s_waitcnt lgkmcnt(0)" ::: "memory"); \
    __builtin_amdgcn_sched_barrier(0); } while (0)

#define MFMA16(a, b, c) __builtin_amdgcn_mfma_f32_16x16x32_bf16((a), (b), (c), 0, 0, 0)

// ---------------------------------------------------------------------------
// prep: blocks [0,3072) cast f32->bf16 [w | Wq | Wk | Wv | Wr]; blocks
// [3072, 11262) build sinusoidal r [LR x DM] bf16.
// ---------------------------------------------------------------------------
__global__ __launch_bounds__(256)
void prep(const float* __restrict__ w, const float* __restrict__ Wq,
          const float* __restrict__ Wk, const float* __restrict__ Wv,
          const float* __restrict__ Wr, unsigned short* __restrict__ dst,
          unsigned short* __restrict__ r) {
    int b = blockIdx.x;
    if (b < 3072) {
        size_t e0 = ((size_t)b * 256 + threadIdx.x) * 8;
        const float* src;
        if (e0 < (size_t)LQ * DM) src = w + e0;
        else {
            size_t ro = e0 - (size_t)LQ * DM;
            int wi = (int)(ro >> 20);
            size_t off = ro & 1048575;
            src = (wi == 0 ? Wq : wi == 1 ? Wk : wi == 2 ? Wv : Wr) + off;
        }
        f4v a = *(const f4v*)src;
        f4v c = *(const f4v*)(src + 4);
        us8 o;
        o[0]=f2bf(a[0]); o[1]=f2bf(a[1]); o[2]=f2bf(a[2]); o[3]=f2bf(a[3]);
        o[4]=f2bf(c[0]); o[5]=f2bf(c[1]); o[6]=f2bf(c[2]); o[7]=f2bf(c[3]);
        *(us8*)(dst + e0) = o;
    } else {
        int tg = (b - 3072) * 256 + threadIdx.x;   // LR*512 exactly
        int gm = tg >> 9, c2 = tg & 511;
        float invf = expf(-(float)c2 * (9.210340371976184f / 512.0f));
        float ang = (float)(gm - (LQ - 1)) * invf;
        us2 o; o[0] = f2bf(sinf(ang)); o[1] = f2bf(cosf(ang));
        *(us2*)&r[(size_t)gm * DM + c2 * 2] = o;
    }
}

// ---------------------------------------------------------------------------
// All 4 projections in one dispatch. C[M,N]=A@B^T bf16, 64x128 tile, BK=64,
// global_load_lds(16), linear LDS. mat==2 writes C transposed (vt[n][m]).
// blocks [0,768): QKV (mat=bid>>8); blocks [768,1280): rp (mat=3).
// ---------------------------------------------------------------------------
__global__ __launch_bounds__(256)
void proj_all(const unsigned short* __restrict__ wbf, const unsigned short* __restrict__ rr,
              const unsigned short* __restrict__ Wqb, const unsigned short* __restrict__ Wkb,
              const unsigned short* __restrict__ Wvb, const unsigned short* __restrict__ Wrb,
              unsigned short* __restrict__ qb, unsigned short* __restrict__ kkb,
              unsigned short* __restrict__ vtg, unsigned short* __restrict__ rp) {
    __shared__ unsigned short As[64 * 64];
    __shared__ unsigned short Bs[128 * 64];
    int bid = blockIdx.x;
    int mat, mblk, nblk;
    if (bid < 768) { mat = bid >> 8; int rm = bid & 255; mblk = rm >> 3; nblk = rm & 7; }
    else           { mat = 3; int rm = bid - 768; mblk = rm >> 3; nblk = rm & 7; }
    const int M = (mat < 3) ? LQ : LR;
    const unsigned short* A = (mat < 3) ? wbf : rr;
    const unsigned short* B = mat == 0 ? Wqb : mat == 1 ? Wkb : mat == 2 ? Wvb : Wrb;
    unsigned short* C = mat == 0 ? qb : mat == 1 ? kkb : mat == 2 ? vtg : rp;
    const int m0 = mblk * 64, n0 = nblk * 128;
    const int t = threadIdx.x;
    const int w = t >> 6, lan16 = t & 15, lgrp = (t & 63) >> 4;
    const int wm = (w >> 1) * 32, wn = (w & 1) * 64;
    f4v acc[2][4] = {};

    for (int k0 = 0; k0 < DM; k0 += 64) {
        #pragma unroll
        for (int it = 0; it < 2; ++it) {
            int slot = it * 256 + t;
            int row = slot >> 3, c8 = slot & 7;
            int gm = m0 + row; if (gm > M - 1) gm = M - 1;
            GLOAD16(A + (size_t)gm * DM + k0 + c8 * 8,
                    (char*)As + (size_t)(it * 256 + w * 64) * 16);
        }
        #pragma unroll
        for (int it = 0; it < 4; ++it) {
            int slot = it * 256 + t;
            int row = slot >> 3, c8 = slot & 7;
            GLOAD16(B + (size_t)(n0 + row) * DM + k0 + c8 * 8,
                    (char*)Bs + (size_t)(it * 256 + w * 64) * 16);
        }
        __syncthreads();
        #pragma unroll
        for (int kk = 0; kk < 2; ++kk) {
            s8v aF[2], bF[4];
            #pragma unroll
            for (int i = 0; i < 2; ++i)
                aF[i] = *(const s8v*)&As[(wm + i * 16 + lan16) * 64 + kk * 32 + lgrp * 8];
            #pragma unroll
            for (int j = 0; j < 4; ++j)
                bF[j] = *(const s8v*)&Bs[(wn + j * 16 + lan16) * 64 + kk * 32 + lgrp * 8];
            #pragma unroll
            for (int i = 0; i < 2; ++i)
                #pragma unroll
                for (int j = 0; j < 4; ++j)
                    acc[i][j] = MFMA16(aF[i], bF[j], acc[i][j]);
        }
        __syncthreads();
    }
    if (mat != 2) {
        #pragma unroll
        for (int i = 0; i < 2; ++i)
            #pragma unroll
            for (int j = 0; j < 4; ++j)
                #pragma unroll
                for (int rg = 0; rg < 4; ++rg) {
                    int row = m0 + wm + i * 16 + lgrp * 4 + rg;
                    if (row < M)
                        C[(size_t)row * DM + n0 + wn + j * 16 + lan16] = f2bf(acc[i][j][rg]);
                }
    } else {
        #pragma unroll
        for (int i = 0; i < 2; ++i)
            #pragma unroll
            for (int j = 0; j < 4; ++j) {
                int n = n0 + wn + j * 16 + lan16;
                int m = m0 + wm + i * 16 + lgrp * 4;
                u32x2 pp;
                pp[0] = cvtpk(acc[i][j][0], acc[i][j][1]);
                pp[1] = cvtpk(acc[i][j][2], acc[i][j][3]);
                *(u32x2*)&C[(size_t)n * LQ + m] = pp;
            }
    }
}

// ---------------------------------------------------------------------------
// Fused rel-attention, split-j, BARRIER-FREE. Block = (head, 64 q rows,
// j-half); 4 independent waves. All MFMA B-operands loaded directly from
// global (L1/L2-served); LDS only for the wave-private shear buffers.
// Fixed-max softmax; rel-shift masks fall out of the rp row-bounds check
// (j==i+1 slot maps exactly to trow==LR / trow==-1 -> zero).
// ---------------------------------------------------------------------------
__global__ __launch_bounds__(256, 4)
void attn_mfma(const unsigned short* __restrict__ q, const unsigned short* __restrict__ kkg,
               const unsigned short* __restrict__ vtg, const unsigned short* __restrict__ rp,
               const float* __restrict__ ub, const float* __restrict__ vb,
               float* __restrict__ Oa, float* __restrict__ Ob,
               float* __restrict__ la, float* __restrict__ lb) {
    __shared__ unsigned short Gtw[4][80 * 18];
    __shared__ unsigned short Pt[4][64 * 18];

    // XCD swizzle: 1024 = 8 x 128 (2 heads per XCD chunk)
    const int dd = blockIdx.x;
    const int f = (dd & 7) * 128 + (dd >> 3);
    const int h = f >> 6;
    const int sp = (f >> 5) & 1;
    const int i0 = (f & 31) * 64;
    const int col0 = h * DH;
    float* Op = sp ? Ob : Oa;
    float* lp = sp ? lb : la;
    const int jbeg = sp * 1024;

    const int t = threadIdx.x;
    const int w = t >> 6, lan16 = t & 15, lgrp = (t & 63) >> 4;
    const int W = w * 16;
    const int cbase = 48 - W;
    const float C1 = 0.125f * 1.4426950408889634f;
    const float C0 = -4.0f * 1.4426950408889634f;

    unsigned short* gw = Gtw[w];
    unsigned short* pw = Pt[w];

    // Q fragments direct from global + f32 bias, packed via v_cvt_pk_bf16_f32
    union uv { u32x4 u; s8v s; };
    auto mkfrag = [&](int gi, const float* bias, s8v* dstf) {
        #pragma unroll
        for (int kk = 0; kk < 2; ++kk) {
            int cb = kk * 32 + lgrp * 8;
            us8 qv = (us8){0,0,0,0,0,0,0,0};
            if (gi < LQ) qv = *(const us8*)(q + (size_t)gi * DM + col0 + cb);
            f4v b0 = *(const f4v*)(bias + col0 + cb);
            f4v b1 = *(const f4v*)(bias + col0 + cb + 4);
            uv o;
            o.u[0] = cvtpk(bf2f(qv[0]) + b0[0], bf2f(qv[1]) + b0[1]);
            o.u[1] = cvtpk(bf2f(qv[2]) + b0[2], bf2f(qv[3]) + b0[3]);
            o.u[2] = cvtpk(bf2f(qv[4]) + b1[0], bf2f(qv[5]) + b1[1]);
            o.u[3] = cvtpk(bf2f(qv[6]) + b1[2], bf2f(qv[7]) + b1[3]);
            dstf[kk] = o.s;
        }
    };
    s8v quF[2], qvlF[2], qvsF[2];
    mkfrag(i0 + W + lan16, ub, quF);
    mkfrag(i0 + W + lan16, vb, qvlF);
    mkfrag(i0 + W + 1 + lan16, vb, qvsF);

    f4v accO[4] = {};
    float lsum[4] = {0.f, 0.f, 0.f, 0.f};

    for (int tt = 0; tt < 16; ++tt) {
        const int j0 = jbeg + tt * 64;
        const int rel = j0 - i0;

        // AC = QU @ K^T : B-fragments straight from kkg
        f4v acF[4] = {};
        #pragma unroll
        for (int nf = 0; nf < 4; ++nf) {
            const unsigned short* kp = kkg + (size_t)(j0 + nf * 16 + lan16) * DM + col0;
            #pragma unroll
            for (int kk = 0; kk < 2; ++kk) {
                us8 bv = *(const us8*)(kp + kk * 32 + lgrp * 8);
                acF[nf] = MFMA16(quF[kk], (s8v)bv, acF[nf]);
            }
        }
        // BD: G = QV @ band^T, band rows straight from rp with bounds mask
        f4v g[5] = {};
        auto bd_pass = [&](const s8v* qf, int base) {
            #pragma unroll
            for (int c = 0; c < 5; ++c) {
                int trow = base + cbase + c * 16 + lan16;
                bool ok = (trow >= 0) && (trow < LR);
                const unsigned short* bp = rp + (size_t)trow * DM + col0;
                #pragma unroll
                for (int kk = 0; kk < 2; ++kk) {
                    us8 bv = (us8){0,0,0,0,0,0,0,0};
                    if (ok) bv = *(const us8*)(bp + kk * 32 + lgrp * 8);
                    g[c] = MFMA16(qf[kk], (s8v)bv, g[c]);
                }
            }
        };
        if (rel < 0)      bd_pass(qvlF, rel + 4031);
        else if (rel > 0) bd_pass(qvsF, rel - 65);
        else { bd_pass(qvlF, 4031); bd_pass(qvsF, -65); }  // diag: disjoint regions

        // sheared G store (b32 cvt_pk pairs), pitch 18
        #pragma unroll
        for (int c = 0; c < 5; ++c) {
            int cl = c * 16 + lan16;
            *(unsigned*)&gw[cl * 18 + lgrp * 4]     = cvtpk(g[c][0], g[c][1]);
            *(unsigned*)&gw[cl * 18 + lgrp * 4 + 2] = cvtpk(g[c][2], g[c][3]);
        }
        WAVE_LDS_FENCE();   // cross-lane handoff: G stores -> softmax reads

        // fixed-max softmax; P -> P^T[jl][rhat] (pitch 18)
        #pragma unroll
        for (int nf = 0; nf < 4; ++nf) {
            int jl = nf * 16 + lan16;
            float pp[4];
            #pragma unroll
            for (int rg = 0; rg < 4; ++rg) {
                const int rhat = lgrp * 4 + rg;
                float bd = bf2f(gw[(jl - rhat + 15) * 18 + rhat]);
                pp[rg] = exp2f(fmaf(acF[nf][rg] + bd, C1, C0));
                lsum[rg] += pp[rg];
            }
            *(unsigned*)&pw[jl * 18 + lgrp * 4]     = cvtpk(pp[0], pp[1]);
            *(unsigned*)&pw[jl * 18 + lgrp * 4 + 2] = cvtpk(pp[2], pp[3]);
        }
        WAVE_LDS_FENCE();   // cross-lane handoff: P stores -> pF gather

        // pF gather from P^T
        s8v pF[2];
        #pragma unroll
        for (int kk = 0; kk < 2; ++kk) {
            us8 tmp;
            #pragma unroll
            for (int e = 0; e < 8; ++e)
                tmp[e] = pw[(kk * 32 + lgrp * 8 + e) * 18 + lan16];
            pF[kk] = (s8v)tmp;
        }
        // PV: V-fragments straight from pre-transposed vtg
        #pragma unroll
        for (int nf = 0; nf < 4; ++nf) {
            const unsigned short* vp = vtg + (size_t)(col0 + nf * 16 + lan16) * LQ + j0;
            #pragma unroll
            for (int kk = 0; kk < 2; ++kk) {
                us8 bv = *(const us8*)(vp + kk * 32 + lgrp * 8);
                accO[nf] = MFMA16(pF[kk], (s8v)bv, accO[nf]);
            }
        }
    }

    // epilogue: partial row-sums (DPP) + unnormalized O partial
    #pragma unroll
    for (int rg = 0; rg < 4; ++rg) {
        float s = lsum[rg];
        s += rot16<0x121>(s);
        s += rot16<0x122>(s);
        s += rot16<0x124>(s);
        s += rot16<0x128>(s);
        const int row = i0 + W + lgrp * 4 + rg;
        if (lan16 == 0) lp[h * LQ + row] = s;
        #pragma unroll
        for (int nf = 0; nf < 4; ++nf)
            Op[(size_t)row * DM + col0 + nf * 16 + lan16] = accO[nf][rg];
    }
}

// ---------------------------------------------------------------------------
// combine: out = (Oa + Ob) / (la + lb)
// ---------------------------------------------------------------------------
__global__ __launch_bounds__(256)
void combine(const float* __restrict__ Oa, const float* __restrict__ Ob,
             const float* __restrict__ la, const float* __restrict__ lb,
             float* __restrict__ out) {
    int i = blockIdx.x * 256 + threadIdx.x;   // f4 index
    int e0 = i * 4;
    int row = e0 >> 10;
    int h = (e0 & 1023) >> 6;
    float inv = 1.f / (la[h * LQ + row] + lb[h * LQ + row]);
    f4v a = *(const f4v*)(Oa + e0);
    f4v b = *(const f4v*)(Ob + e0);
    f4v o = (a + b) * inv;
    *(f4v*)(out + e0) = o;
}

// ---------------------------------------------------------------------------
extern "C" void kernel_launch(void* const* d_in, const int* in_sizes, int n_in,
                              void* d_out, int out_size, void* d_ws, size_t ws_size,
                              hipStream_t stream) {
    const float* w  = (const float*)d_in[0];
    const float* Wq = (const float*)d_in[1];
    const float* Wk = (const float*)d_in[2];
    const float* Wv = (const float*)d_in[3];
    const float* Wr = (const float*)d_in[4];
    const float* ub = (const float*)d_in[5];
    const float* vb = (const float*)d_in[6];
    float* out = (float*)d_out;

    const size_t U = 1048576;  // 1M shorts = 2MB
    unsigned short* ws = (unsigned short*)d_ws;
    unsigned short* wbf = ws;            // 2U
    unsigned short* Wqb = ws + 2 * U;
    unsigned short* Wkb = ws + 3 * U;
    unsigned short* Wvb = ws + 4 * U;
    unsigned short* Wrb = ws + 5 * U;
    unsigned short* qb  = ws + 6 * U;    // 2U
    unsigned short* kkb = ws + 8 * U;    // 2U
    unsigned short* vtg = ws + 10 * U;   // 2U (transposed V, [DM][LQ])
    unsigned short* rp  = ws + 12 * U;   // 4U (LR*DM)
    unsigned short* r   = ws + 16 * U;   // 4U

    // overlays (dead regions during attn):
    float* Oa = (float*)(ws + 16 * U);   // over r
    float* Ob = (float*)(ws);            // over wbf..Wkb
    float* la = (float*)(ws + 4 * U);    // over Wvb
    float* lb = la + NH * LQ;

    dim3 blk(256);
    hipLaunchKernelGGL(prep, dim3(11262), blk, 0, stream, w, Wq, Wk, Wv, Wr, wbf, r);
    hipLaunchKernelGGL(proj_all, dim3(1280), blk, 0, stream,
                       wbf, r, Wqb, Wkb, Wvb, Wrb, qb, kkb, vtg, rp);
    hipLaunchKernelGGL(attn_mfma, dim3(1024), blk, 0, stream,
                       qb, kkb, vtg, rp, ub, vb, Oa, Ob, la, lb);
    hipLaunchKernelGGL(combine, dim3(2048), blk, 0, stream, Oa, Ob, la, lb, out);
}

// Round 8
// 141.340 us; speedup vs baseline: 1.9861x; 1.9861x over previous
//
#include <hip/hip_runtime.h>
#include <math.h>
#include <stddef.h>

#define LQ 2048
#define DM 1024
#define NH 16
#define DH 64
#define LR 4095  // 2*LQ-1

typedef __attribute__((ext_vector_type(4))) float f4v;
typedef __attribute__((ext_vector_type(8))) short s8v;
typedef __attribute__((ext_vector_type(2))) unsigned short us2;
typedef __attribute__((ext_vector_type(8))) unsigned short us8;
typedef __attribute__((ext_vector_type(2))) unsigned int u32x2;
typedef __attribute__((ext_vector_type(4))) unsigned int u32x4;

__device__ __forceinline__ unsigned short f2bf(float x) {
    unsigned int u = __float_as_uint(x);
    return (unsigned short)((u + 0x7FFFu + ((u >> 16) & 1u)) >> 16);
}
__device__ __forceinline__ float bf2f(unsigned short s) {
    return __uint_as_float(((unsigned int)s) << 16);
}
__device__ __forceinline__ unsigned cvtpk(float lo, float hi) {
    unsigned r;
    asm("v_cvt_pk_bf16_f32 %0, %1, %2" : "=v"(r) : "v"(lo), "v"(hi));
    return r;
}
template<int CTRL>
__device__ __forceinline__ float rot16(float x) {
    return __uint_as_float((unsigned)__builtin_amdgcn_update_dpp(
        0, (int)__float_as_uint(x), CTRL, 0xF, 0xF, false));
}
#define GLOAD16(g, l) __builtin_amdgcn_global_load_lds((g), (l), 16, 0, 0)
// fence for cross-lane LDS handoff within a wave (load-bearing! r5 NaN)
#define WAVE_LDS_FENCE() do { \
    asm volatile("s_waitcnt lgkmcnt(0)" ::: "memory"); \
    __builtin_amdgcn_sched_barrier(0); } while (0)

#define MFMA16(a, b, c) __builtin_amdgcn_mfma_f32_16x16x32_bf16((a), (b), (c), 0, 0, 0)

// swizzled read from linear-DMA-staged tile: byte ^= (row&7)<<4 (source was
// pre-swizzled col c8^(row&7), so this recovers global[row][colshort/8])
__device__ __forceinline__ s8v sw_read8(const unsigned short* base, int row, int colshort) {
    int byte = (row * 128 + colshort * 2) ^ ((row & 7) << 4);
    return *(const s8v*)((const char*)base + byte);
}

// ---------------------------------------------------------------------------
// prep: [0,3072) cast f32->bf16 [w|Wq|Wk|Wv|Wr]; [3072,11262) sinusoid r;
// [11262,11390) zero the 128-row guards around rp.
// ---------------------------------------------------------------------------
__global__ __launch_bounds__(256)
void prep(const float* __restrict__ w, const float* __restrict__ Wq,
          const float* __restrict__ Wk, const float* __restrict__ Wv,
          const float* __restrict__ Wr, unsigned short* __restrict__ dst,
          unsigned short* __restrict__ r, unsigned short* __restrict__ rpg) {
    int b = blockIdx.x;
    if (b < 3072) {
        size_t e0 = ((size_t)b * 256 + threadIdx.x) * 8;
        const float* src;
        if (e0 < (size_t)LQ * DM) src = w + e0;
        else {
            size_t ro = e0 - (size_t)LQ * DM;
            int wi = (int)(ro >> 20);
            size_t off = ro & 1048575;
            src = (wi == 0 ? Wq : wi == 1 ? Wk : wi == 2 ? Wv : Wr) + off;
        }
        f4v a = *(const f4v*)src;
        f4v c = *(const f4v*)(src + 4);
        us8 o;
        o[0]=f2bf(a[0]); o[1]=f2bf(a[1]); o[2]=f2bf(a[2]); o[3]=f2bf(a[3]);
        o[4]=f2bf(c[0]); o[5]=f2bf(c[1]); o[6]=f2bf(c[2]); o[7]=f2bf(c[3]);
        *(us8*)(dst + e0) = o;
    } else if (b < 11262) {
        int tg = (b - 3072) * 256 + threadIdx.x;   // LR*512 exactly
        int gm = tg >> 9, c2 = tg & 511;
        float invf = expf(-(float)c2 * (9.210340371976184f / 512.0f));
        float ang = (float)(gm - (LQ - 1)) * invf;
        us2 o; o[0] = f2bf(sinf(ang)); o[1] = f2bf(cosf(ang));
        *(us2*)&r[(size_t)gm * DM + c2 * 2] = o;
    } else {
        int idx = (b - 11262) * 2048 + threadIdx.x * 8;  // [0, 262144)
        unsigned short* p = (idx < 131072)
            ? (rpg - 131072 + idx)
            : (rpg + (size_t)LR * DM + (idx - 131072));
        *(us8*)p = (us8){0,0,0,0,0,0,0,0};
    }
}

// ---------------------------------------------------------------------------
// All 4 projections in one dispatch. C[M,N]=A@B^T bf16, 64x128 tile, BK=64,
// global_load_lds(16), linear LDS. mat==2 writes C transposed (vt[n][m]).
// ---------------------------------------------------------------------------
__global__ __launch_bounds__(256)
void proj_all(const unsigned short* __restrict__ wbf, const unsigned short* __restrict__ rr,
              const unsigned short* __restrict__ Wqb, const unsigned short* __restrict__ Wkb,
              const unsigned short* __restrict__ Wvb, const unsigned short* __restrict__ Wrb,
              unsigned short* __restrict__ qb, unsigned short* __restrict__ kkb,
              unsigned short* __restrict__ vtg, unsigned short* __restrict__ rpg) {
    __shared__ unsigned short As[64 * 64];
    __shared__ unsigned short Bs[128 * 64];
    int bid = blockIdx.x;
    int mat, mblk, nblk;
    if (bid < 768) { mat = bid >> 8; int rm = bid & 255; mblk = rm >> 3; nblk = rm & 7; }
    else           { mat = 3; int rm = bid - 768; mblk = rm >> 3; nblk = rm & 7; }
    const int M = (mat < 3) ? LQ : LR;
    const unsigned short* A = (mat < 3) ? wbf : rr;
    const unsigned short* B = mat == 0 ? Wqb : mat == 1 ? Wkb : mat == 2 ? Wvb : Wrb;
    unsigned short* C = mat == 0 ? qb : mat == 1 ? kkb : mat == 2 ? vtg : rpg;
    const int m0 = mblk * 64, n0 = nblk * 128;
    const int t = threadIdx.x;
    const int w = t >> 6, lan16 = t & 15, lgrp = (t & 63) >> 4;
    const int wm = (w >> 1) * 32, wn = (w & 1) * 64;
    f4v acc[2][4] = {};

    for (int k0 = 0; k0 < DM; k0 += 64) {
        #pragma unroll
        for (int it = 0; it < 2; ++it) {
            int slot = it * 256 + t;
            int row = slot >> 3, c8 = slot & 7;
            int gm = m0 + row; if (gm > M - 1) gm = M - 1;
            GLOAD16(A + (size_t)gm * DM + k0 + c8 * 8,
                    (char*)As + (size_t)(it * 256 + w * 64) * 16);
        }
        #pragma unroll
        for (int it = 0; it < 4; ++it) {
            int slot = it * 256 + t;
            int row = slot >> 3, c8 = slot & 7;
            GLOAD16(B + (size_t)(n0 + row) * DM + k0 + c8 * 8,
                    (char*)Bs + (size_t)(it * 256 + w * 64) * 16);
        }
        __syncthreads();
        #pragma unroll
        for (int kk = 0; kk < 2; ++kk) {
            s8v aF[2], bF[4];
            #pragma unroll
            for (int i = 0; i < 2; ++i)
                aF[i] = *(const s8v*)&As[(wm + i * 16 + lan16) * 64 + kk * 32 + lgrp * 8];
            #pragma unroll
            for (int j = 0; j < 4; ++j)
                bF[j] = *(const s8v*)&Bs[(wn + j * 16 + lan16) * 64 + kk * 32 + lgrp * 8];
            #pragma unroll
            for (int i = 0; i < 2; ++i)
                #pragma unroll
                for (int j = 0; j < 4; ++j)
                    acc[i][j] = MFMA16(aF[i], bF[j], acc[i][j]);
        }
        __syncthreads();
    }
    if (mat != 2) {
        #pragma unroll
        for (int i = 0; i < 2; ++i)
            #pragma unroll
            for (int j = 0; j < 4; ++j)
                #pragma unroll
                for (int rg = 0; rg < 4; ++rg) {
                    int row = m0 + wm + i * 16 + lgrp * 4 + rg;
                    if (row < M)
                        C[(size_t)row * DM + n0 + wn + j * 16 + lan16] = f2bf(acc[i][j][rg]);
                }
    } else {
        #pragma unroll
        for (int i = 0; i < 2; ++i)
            #pragma unroll
            for (int j = 0; j < 4; ++j) {
                int n = n0 + wn + j * 16 + lan16;
                int m = m0 + wm + i * 16 + lgrp * 4;
                u32x2 pp;
                pp[0] = cvtpk(acc[i][j][0], acc[i][j][1]);
                pp[1] = cvtpk(acc[i][j][2], acc[i][j][3]);
                *(u32x2*)&C[(size_t)n * LQ + m] = pp;
            }
    }
}

// ---------------------------------------------------------------------------
// Fused rel-attention, split-j, pipelined. Block = (head, 64 q rows, j-half).
// K+band double-buffered via global_load_lds (pre-swizzled source), V single-
// buffered; counted vmcnt(8)/vmcnt(6) + raw s_barrier (no full drains).
// Fixed-max softmax; rel-shift masks via 128 zero guard rows around rp.
// ---------------------------------------------------------------------------
__global__ __launch_bounds__(256, 2)
void attn_mfma(const unsigned short* __restrict__ q, const unsigned short* __restrict__ kkg,
               const unsigned short* __restrict__ vtg, const unsigned short* __restrict__ rpg,
               const float* __restrict__ ub, const float* __restrict__ vb,
               float* __restrict__ Oa, float* __restrict__ Ob,
               float* __restrict__ la, float* __restrict__ lb) {
    __shared__ unsigned short Kb[2][64 * 64];
    __shared__ unsigned short Bb[2][128 * 64];
    __shared__ unsigned short Vb[64 * 64];
    __shared__ unsigned short Gtw[4][80 * 20];
    __shared__ unsigned short Pt[4][64 * 18];

    // XCD swizzle: 1024 = 8 x 128
    const int dd = blockIdx.x;
    const int f = (dd & 7) * 128 + (dd >> 3);
    const int h = f >> 6;
    const int sp = (f >> 5) & 1;
    const int i0 = (f & 31) * 64;
    const int col0 = h * DH;
    float* Op = sp ? Ob : Oa;
    float* lp = sp ? lb : la;
    const int jbeg = sp * 1024;

    const int t = threadIdx.x;
    const int w = t >> 6, lan16 = t & 15, lgrp = (t & 63) >> 4;
    const int W = w * 16;
    const int cbase = 48 - W;
    const float C1 = 0.125f * 1.4426950408889634f;
    const float C0 = -4.0f * 1.4426950408889634f;

    unsigned short* gw = Gtw[w];
    unsigned short* pw = Pt[w];

    // Q fragments direct from global + f32 bias (proven r7)
    union uv { u32x4 u; s8v s; };
    auto mkfrag = [&](int gi, const float* bias, s8v* dstf) {
        #pragma unroll
        for (int kk = 0; kk < 2; ++kk) {
            int cb = kk * 32 + lgrp * 8;
            us8 qv = (us8){0,0,0,0,0,0,0,0};
            if (gi < LQ) qv = *(const us8*)(q + (size_t)gi * DM + col0 + cb);
            f4v b0 = *(const f4v*)(bias + col0 + cb);
            f4v b1 = *(const f4v*)(bias + col0 + cb + 4);
            uv o;
            o.u[0] = cvtpk(bf2f(qv[0]) + b0[0], bf2f(qv[1]) + b0[1]);
            o.u[1] = cvtpk(bf2f(qv[2]) + b0[2], bf2f(qv[3]) + b0[3]);
            o.u[2] = cvtpk(bf2f(qv[4]) + b1[0], bf2f(qv[5]) + b1[1]);
            o.u[3] = cvtpk(bf2f(qv[6]) + b1[2], bf2f(qv[7]) + b1[3]);
            dstf[kk] = o.s;
        }
    };
    s8v quF[2], qvlF[2], qvsF[2];
    mkfrag(i0 + W + lan16, ub, quF);
    mkfrag(i0 + W + lan16, vb, qvlF);
    mkfrag(i0 + W + 1 + lan16, vb, qvsF);

    // DMA staging: linear LDS dest (wave base + lane*16), pre-swizzled source
    auto stageK = [&](int j0, int buf) {
        #pragma unroll
        for (int it = 0; it < 2; ++it) {
            int slot = it * 256 + t;
            int row = slot >> 3, c8 = (t & 7) ^ (row & 7);
            GLOAD16(kkg + (size_t)(j0 + row) * DM + col0 + c8 * 8,
                    (char*)&Kb[buf][0] + (size_t)(it * 256 + (t & ~63)) * 16);
        }
    };
    auto stageB = [&](int rel, int buf) {
        int base = (rel <= 0) ? rel + 4031 : rel - 65;
        #pragma unroll
        for (int it = 0; it < 4; ++it) {
            int slot = it * 256 + t;
            int row = slot >> 3, c8 = (t & 7) ^ (row & 7);
            GLOAD16(rpg + (ptrdiff_t)(base + row) * DM + col0 + c8 * 8,
                    (char*)&Bb[buf][0] + (size_t)(it * 256 + (t & ~63)) * 16);
        }
    };
    auto stageV = [&](int j0) {
        #pragma unroll
        for (int it = 0; it < 2; ++it) {
            int slot = it * 256 + t;
            int row = slot >> 3, c8 = (t & 7) ^ (row & 7);
            GLOAD16(vtg + (size_t)(col0 + row) * LQ + j0 + c8 * 8,
                    (char*)&Vb[0] + (size_t)(it * 256 + (t & ~63)) * 16);
        }
    };

    f4v accO[4] = {};
    float lsum[4] = {0.f, 0.f, 0.f, 0.f};

    stageK(jbeg, 0);
    stageB(jbeg - i0, 0);

    int cur = 0;
    for (int tt = 0; tt < 16; ++tt) {
        const int j0 = jbeg + tt * 64;
        const int rel = j0 - i0;
        stageV(j0);                           // 2 VMEM
        const int tn = (tt < 15) ? tt + 1 : 15;
        stageK(jbeg + tn * 64, cur ^ 1);      // 2 VMEM
        stageB(jbeg + tn * 64 - i0, cur ^ 1); // 4 VMEM
        __builtin_amdgcn_sched_barrier(0);
        asm volatile("s_waitcnt vmcnt(8)" ::: "memory");  // K/band of tile t done
        __builtin_amdgcn_s_barrier();
        __builtin_amdgcn_sched_barrier(0);

        // AC = QU @ K^T
        f4v acF[4] = {};
        #pragma unroll
        for (int nf = 0; nf < 4; ++nf)
            #pragma unroll
            for (int kk = 0; kk < 2; ++kk) {
                s8v bF = sw_read8(&Kb[cur][0], nf * 16 + lan16, kk * 32 + lgrp * 8);
                acF[nf] = MFMA16(quF[kk], bF, acF[nf]);
            }
        // BD: G = QV @ band^T (staged band; guards encode the region mask)
        f4v g[5] = {};
        {
            const s8v* qf = (rel <= 0) ? qvlF : qvsF;
            #pragma unroll
            for (int c = 0; c < 5; ++c)
                #pragma unroll
                for (int kk = 0; kk < 2; ++kk) {
                    s8v bF = sw_read8(&Bb[cur][0], cbase + c * 16 + lan16, kk * 32 + lgrp * 8);
                    g[c] = MFMA16(qf[kk], bF, g[c]);
                }
        }
        if (rel == 0) {   // diag tile: upper band direct from global (once/block)
            #pragma unroll
            for (int c = 0; c < 5; ++c) {
                int trow = -65 + cbase + c * 16 + lan16;
                const unsigned short* bp = rpg + (ptrdiff_t)trow * DM + col0;
                #pragma unroll
                for (int kk = 0; kk < 2; ++kk) {
                    us8 bv = *(const us8*)(bp + kk * 32 + lgrp * 8);
                    g[c] = MFMA16(qvsF[kk], (s8v)bv, g[c]);
                }
            }
        }
        // sheared G store, b64-packed (pitch 20 -> 8B aligned)
        #pragma unroll
        for (int c = 0; c < 5; ++c) {
            int cl = c * 16 + lan16;
            u32x2 pp;
            pp[0] = cvtpk(g[c][0], g[c][1]);
            pp[1] = cvtpk(g[c][2], g[c][3]);
            *(u32x2*)&gw[cl * 20 + lgrp * 4] = pp;
        }
        WAVE_LDS_FENCE();   // G stores -> softmax reads

        // fixed-max softmax; P -> P^T[jl][rhat] (pitch 18)
        #pragma unroll
        for (int nf = 0; nf < 4; ++nf) {
            int jl = nf * 16 + lan16;
            float pp[4];
            #pragma unroll
            for (int rg = 0; rg < 4; ++rg) {
                const int rhat = lgrp * 4 + rg;
                float bd = bf2f(gw[(jl - rhat + 15) * 20 + rhat]);
                pp[rg] = exp2f(fmaf(acF[nf][rg] + bd, C1, C0));
                lsum[rg] += pp[rg];
            }
            *(unsigned*)&pw[jl * 18 + lgrp * 4]     = cvtpk(pp[0], pp[1]);
            *(unsigned*)&pw[jl * 18 + lgrp * 4 + 2] = cvtpk(pp[2], pp[3]);
        }
        WAVE_LDS_FENCE();   // P stores -> pF gather

        s8v pF[2];
        #pragma unroll
        for (int kk = 0; kk < 2; ++kk) {
            us8 tmp;
            #pragma unroll
            for (int e = 0; e < 8; ++e)
                tmp[e] = pw[(kk * 32 + lgrp * 8 + e) * 18 + lan16];
            pF[kk] = (s8v)tmp;
        }
        __builtin_amdgcn_sched_barrier(0);
        asm volatile("s_waitcnt vmcnt(6)" ::: "memory");  // V of tile t done
        __builtin_amdgcn_s_barrier();
        __builtin_amdgcn_sched_barrier(0);

        // PV
        #pragma unroll
        for (int nf = 0; nf < 4; ++nf)
            #pragma unroll
            for (int kk = 0; kk < 2; ++kk) {
                s8v vF = sw_read8(&Vb[0], nf * 16 + lan16, kk * 32 + lgrp * 8);
                accO[nf] = MFMA16(pF[kk], vF, accO[nf]);
            }
        __builtin_amdgcn_sched_barrier(0);
        __builtin_amdgcn_s_barrier();   // end: protect Vb (and cur bufs) for next DMA
        __builtin_amdgcn_sched_barrier(0);
        cur ^= 1;
    }

    // epilogue: partial row-sums (DPP) + unnormalized O partial
    #pragma unroll
    for (int rg = 0; rg < 4; ++rg) {
        float s = lsum[rg];
        s += rot16<0x121>(s);
        s += rot16<0x122>(s);
        s += rot16<0x124>(s);
        s += rot16<0x128>(s);
        const int row = i0 + W + lgrp * 4 + rg;
        if (lan16 == 0) lp[h * LQ + row] = s;
        #pragma unroll
        for (int nf = 0; nf < 4; ++nf)
            Op[(size_t)row * DM + col0 + nf * 16 + lan16] = accO[nf][rg];
    }
}

// ---------------------------------------------------------------------------
// combine: out = (Oa + Ob) / (la + lb)
// ---------------------------------------------------------------------------
__global__ __launch_bounds__(256)
void combine(const float* __restrict__ Oa, const float* __restrict__ Ob,
             const float* __restrict__ la, const float* __restrict__ lb,
             float* __restrict__ out) {
    int i = blockIdx.x * 256 + threadIdx.x;
    int e0 = i * 4;
    int row = e0 >> 10;
    int h = (e0 & 1023) >> 6;
    float inv = 1.f / (la[h * LQ + row] + lb[h * LQ + row]);
    f4v a = *(const f4v*)(Oa + e0);
    f4v b = *(const f4v*)(Ob + e0);
    f4v o = (a + b) * inv;
    *(f4v*)(out + e0) = o;
}

// ---------------------------------------------------------------------------
extern "C" void kernel_launch(void* const* d_in, const int* in_sizes, int n_in,
                              void* d_out, int out_size, void* d_ws, size_t ws_size,
                              hipStream_t stream) {
    const float* w  = (const float*)d_in[0];
    const float* Wq = (const float*)d_in[1];
    const float* Wk = (const float*)d_in[2];
    const float* Wv = (const float*)d_in[3];
    const float* Wr = (const float*)d_in[4];
    const float* ub = (const float*)d_in[5];
    const float* vb = (const float*)d_in[6];
    float* out = (float*)d_out;

    const size_t U = 1048576;  // 1M shorts = 2MB
    unsigned short* ws = (unsigned short*)d_ws;
    unsigned short* wbf = ws;            // 2U
    unsigned short* Wqb = ws + 2 * U;
    unsigned short* Wkb = ws + 3 * U;
    unsigned short* Wvb = ws + 4 * U;
    unsigned short* Wrb = ws + 5 * U;
    unsigned short* qb  = ws + 6 * U;    // 2U
    unsigned short* kkb = ws + 8 * U;    // 2U
    unsigned short* vtg = ws + 10 * U;   // 2U (transposed V, [DM][LQ])
    // guarded rp: 128 zero rows + LR rows + 128 zero rows
    unsigned short* rpg = ws + 12 * U + 131072;                 // interior
    unsigned short* r   = rpg + (size_t)LR * DM + 131072;       // sinusoid (4U)

    // overlays (dead regions during attn):
    float* Oa = (float*)r;               // over r
    float* Ob = (float*)ws;              // over wbf..Wkb
    float* la = (float*)(ws + 4 * U);    // over Wvb
    float* lb = la + NH * LQ;

    dim3 blk(256);
    hipLaunchKernelGGL(prep, dim3(11390), blk, 0, stream, w, Wq, Wk, Wv, Wr, wbf, r, rpg);
    hipLaunchKernelGGL(proj_all, dim3(1280), blk, 0, stream,
                       wbf, r, Wqb, Wkb, Wvb, Wrb, qb, kkb, vtg, rpg);
    hipLaunchKernelGGL(attn_mfma, dim3(1024), blk, 0, stream,
                       qb, kkb, vtg, rpg, ub, vb, Oa, Ob, la, lb);
    hipLaunchKernelGGL(combine, dim3(2048), blk, 0, stream, Oa, Ob, la, lb, out);
}